// Round 4
// baseline (232.659 us; speedup 1.0000x reference)
//
#include <hip/hip_runtime.h>
#include <hip/hip_bf16.h>
#include <cstdint>

// Problem (all inputs/outputs fp32):
//   out[8192][2048] = X[8192][2048] @ Weff[2048][2048]
//   Weff[k][n] = W[k][n] + SCALE * sum_r A[k][r]*Bk[r][n], SCALE = 4/4 = 1.0
//
// Pipeline (2 kernels):
//   prep_wt : fp32 (W + A@Bk)^T -> bf16 Wt [N][K] in d_ws (8MB)
//   gemm_xf32: 128x128 tile, BK=64, mfma_f32_16x16x32_bf16.
//     B-tile: global_load_lds width=16, XOR-chunk swizzle p = c ^ (row&7).
//     A-tile: fused fp32->bf16 staging — float4 global loads (coalesced),
//       VALU cvt, ds_write_b64 into the SAME swizzled layout (per-lane
//       scatter is legal for ds_write; 16-lane beat hits all 32 banks once).
//     Epilogue: nontemporal fp32 stores (don't thrash LLC; X/Wt stay hot).

using bf16 = __hip_bfloat16;
typedef __attribute__((ext_vector_type(8))) __bf16 bf16x8;
typedef __attribute__((ext_vector_type(4))) float f32x4;

constexpr int Mdim = 8192;   // B*S
constexpr int Ndim = 2048;   // NH*HD
constexpr int Kdim = 2048;   // H
constexpr float SCALE = 1.0f;  // ALPHA/RANK = 4/4

constexpr int BM = 128, BN = 128, BK = 64;

__device__ __forceinline__ void gload_lds16(const void* g, void* l) {
  __builtin_amdgcn_global_load_lds(
      (const __attribute__((address_space(1))) uint32_t*)g,
      (__attribute__((address_space(3))) uint32_t*)l,
      16, 0, 0);
}

// ---------------- prep: Weff^T = (W + A@Bk)^T, [N][K] bf16 ----------------
__global__ void prep_wt(const float* __restrict__ W, const float* __restrict__ A,
                        const float* __restrict__ Bk, uint16_t* __restrict__ Wt) {
  __shared__ float tile[64][65];  // [n_local][k_local], +1 pad kills conflicts
  const int tx = threadIdx.x & 63;   // along N on load, along K on store
  const int ty = threadIdx.x >> 6;   // 0..3
  const int n0 = blockIdx.x * 64, k0 = blockIdx.y * 64;

  const int n = n0 + tx;
  const float b0 = Bk[0 * Ndim + n];
  const float b1 = Bk[1 * Ndim + n];
  const float b2 = Bk[2 * Ndim + n];
  const float b3 = Bk[3 * Ndim + n];

  for (int i = ty; i < 64; i += 4) {
    const int k = k0 + i;
    float w = W[(size_t)k * Ndim + n];
    w += SCALE * (A[k * 4 + 0] * b0 + A[k * 4 + 1] * b1 +
                  A[k * 4 + 2] * b2 + A[k * 4 + 3] * b3);
    tile[tx][i] = w;                       // transposed into LDS
  }
  __syncthreads();
  for (int i = ty; i < 64; i += 4) {
    Wt[(size_t)(n0 + i) * Kdim + (k0 + tx)] =
        __bfloat16_as_ushort(__float2bfloat16(tile[i][tx]));
  }
}

// ---------------- main GEMM: C = X(fp32) @ Weff (Wt is Weff^T, K-major) ---
__global__ void gemm_xf32(const float* __restrict__ X,
                          const uint16_t* __restrict__ Wt,
                          float* __restrict__ out) {
  __shared__ uint16_t As[BM * BK];  // 16 KB bf16, swizzled
  __shared__ uint16_t Bs[BN * BK];  // 16 KB bf16, swizzled

  const int t = threadIdx.x;
  const int wave = t >> 6, lane = t & 63;
  const int m0 = blockIdx.y * BM, n0 = blockIdx.x * BN;

  const int wm = wave & 1, wn = wave >> 1;  // 2x2 wave grid, 64x64 each
  const int l15 = lane & 15, kg = lane >> 4;
  const int sw = l15 & 7;                   // frag-read row swizzle key

  // --- B staging (glds): chunk = 8 rows x 64 cols bf16 (1 KB), 16 chunks.
  // lane -> row-in-chunk = lane>>3, global 16B col = (lane&7) ^ (lane>>3).
  const int r8 = lane >> 3;
  const int gcB = (lane & 7) ^ r8;
  const uint16_t* Bg = Wt + (size_t)n0 * Kdim;

  // --- A staging (fused cvt): 16 lanes cover one row's 64 fp32 (256 B).
  // thread -> 8 rows: row_i = wave*32 + i*4 + (lane>>4); k-col = (lane&15)*4.
  const int g4 = lane >> 4;                 // 0..3
  const int cA = l15 >> 1;                  // A chunk 0..7
  const int halfA = l15 & 1;                // 8B half within chunk
  const float* Xg = X + (size_t)m0 * Kdim;

  f32x4 acc[4][4] = {};

  for (int kt = 0; kt < Kdim; kt += BK) {
    // B: async global->LDS
#pragma unroll
    for (int c = 0; c < 4; ++c) {
      const int ch = wave * 4 + c;          // 0..15
      const int row = ch * 8 + r8;
      gload_lds16(Bg + (size_t)row * Kdim + kt + gcB * 8, &Bs[ch * 512]);
    }
    // A: fp32 loads -> cvt -> swizzled ds_write
    float4 av[8];
#pragma unroll
    for (int i = 0; i < 8; ++i) {
      const int row = wave * 32 + i * 4 + g4;
      av[i] = *reinterpret_cast<const float4*>(Xg + (size_t)row * Kdim + kt + l15 * 4);
    }
#pragma unroll
    for (int i = 0; i < 8; ++i) {
      const int row = wave * 32 + i * 4 + g4;
      const int p = cA ^ (row & 7);
      ushort4 o;
      o.x = __bfloat16_as_ushort(__float2bfloat16(av[i].x));
      o.y = __bfloat16_as_ushort(__float2bfloat16(av[i].y));
      o.z = __bfloat16_as_ushort(__float2bfloat16(av[i].z));
      o.w = __bfloat16_as_ushort(__float2bfloat16(av[i].w));
      *reinterpret_cast<uint2*>(&As[row * BK + p * 8 + halfA * 4]) =
          *reinterpret_cast<uint2*>(&o);
    }
    __syncthreads();  // drains vmcnt+lgkm -> tiles visible

#pragma unroll
    for (int s = 0; s < 2; ++s) {           // two 16x16x32 k-steps per BK=64
      bf16x8 af[4], bfr[4];
      const int p = (s * 4 + kg) ^ sw;      // physical chunk for logical k-chunk
#pragma unroll
      for (int i = 0; i < 4; ++i) {
        const int ra = wm * 64 + i * 16 + l15;
        const int rb = wn * 64 + i * 16 + l15;
        af[i]  = *reinterpret_cast<const bf16x8*>(&As[ra * BK + p * 8]);
        bfr[i] = *reinterpret_cast<const bf16x8*>(&Bs[rb * BK + p * 8]);
      }
#pragma unroll
      for (int i = 0; i < 4; ++i)
#pragma unroll
        for (int j = 0; j < 4; ++j)
          acc[i][j] = __builtin_amdgcn_mfma_f32_16x16x32_bf16(af[i], bfr[j], acc[i][j], 0, 0, 0);
    }
    __syncthreads();  // before next stage overwrites tiles
  }

  // epilogue: C/D layout col = lane&15, row = (lane>>4)*4 + reg  [m89/m91]
  // nontemporal: C is write-once, keep LLC for X/Wt re-reads.
#pragma unroll
  for (int i = 0; i < 4; ++i) {
    const int m_base = m0 + wm * 64 + i * 16 + kg * 4;
#pragma unroll
    for (int j = 0; j < 4; ++j) {
      const int n = n0 + wn * 64 + j * 16 + l15;
#pragma unroll
      for (int r = 0; r < 4; ++r) {
        __builtin_nontemporal_store(acc[i][j][r],
                                    &out[(size_t)(m_base + r) * Ndim + n]);
      }
    }
  }
}

extern "C" void kernel_launch(void* const* d_in, const int* in_sizes, int n_in,
                              void* d_out, int out_size, void* d_ws, size_t ws_size,
                              hipStream_t stream) {
  const float* x  = (const float*)d_in[0];  // [4,2048,2048]
  const float* W  = (const float*)d_in[1];  // [2048,16,128]
  const float* A  = (const float*)d_in[2];  // [2048,4]
  const float* Bk = (const float*)d_in[3];  // [4,16,128]
  float* out = (float*)d_out;               // [4,2048,16,128] fp32

  uint16_t* Wt = (uint16_t*)d_ws;           // [2048][2048] Weff^T bf16 (8 MB)

  // Weff^T build
  dim3 g1(Ndim / 64, Kdim / 64);  // 32 x 32
  prep_wt<<<g1, 256, 0, stream>>>(W, A, Bk, Wt);

  // fused cvt + GEMM
  dim3 g2(Ndim / BN, Mdim / BM);  // 16 x 64
  gemm_xf32<<<g2, 256, 0, stream>>>(x, Wt, out);
}

// Round 5
// 200.735 us; speedup vs baseline: 1.1590x; 1.1590x over previous
//
#include <hip/hip_runtime.h>
#include <hip/hip_bf16.h>
#include <cstdint>

// Problem (all inputs/outputs fp32):
//   out[8192][2048] = X[8192][2048] @ Weff[2048][2048]
//   Weff[k][n] = W[k][n] + SCALE * sum_r A[k][r]*Bk[r][n], SCALE = 4/4 = 1.0
//
// Pipeline (2 launches):
//   prep_all: [blocks 0..8191] fp32 X -> bf16 Xb (d_ws)
//             [blocks 8192..9215] fp32 (W + A@Bk)^T -> bf16 Wt [N][K]
//   gemm_bt : 128x128 tile, BK=64, mfma_f32_16x16x32_bf16,
//             global_load_lds width=16, XOR-chunk swizzle p = c ^ (row&7)
//             (bank-conflict-free, verified R3: SQ_LDS_BANK_CONFLICT = 0),
//             XCD patch swizzle: lid&7 -> XCD owns a 16bx x 8by patch
//             (per-XCD L2 working set 33 MB -> 12 MB).
//   Round-4 lesson: do NOT read fp32 X inside the gemm — 16x N-block
//   re-reads amplify fp32 bytes (FETCH 139->266 MB, dur 72->134 us).

using bf16 = __hip_bfloat16;
typedef __attribute__((ext_vector_type(8))) __bf16 bf16x8;
typedef __attribute__((ext_vector_type(4))) float f32x4;

constexpr int Mdim = 8192;   // B*S
constexpr int Ndim = 2048;   // NH*HD
constexpr int Kdim = 2048;   // H
constexpr float SCALE = 1.0f;  // ALPHA/RANK = 4/4

constexpr int BM = 128, BN = 128, BK = 64;
constexpr int CVT_BLOCKS = (Mdim * Kdim) / (256 * 8);  // 8192
constexpr int PREP_BLOCKS = (Ndim / 64) * (Kdim / 64); // 1024

__device__ __forceinline__ void gload_lds16(const void* g, void* l) {
  __builtin_amdgcn_global_load_lds(
      (const __attribute__((address_space(1))) uint32_t*)g,
      (__attribute__((address_space(3))) uint32_t*)l,
      16, 0, 0);
}

// ------------- prep_all: cvt_x (blocks<8192) + Weff^T build --------------
__global__ void prep_all(const float* __restrict__ X,
                         const float* __restrict__ W,
                         const float* __restrict__ A,
                         const float* __restrict__ Bk,
                         uint16_t* __restrict__ Xb,
                         uint16_t* __restrict__ Wt) {
  __shared__ float tile[64][65];  // used by prep part only (+1 pad)

  if (blockIdx.x < CVT_BLOCKS) {
    // ---- fp32 -> bf16, 8 elems/thread, float4 loads ----
    const int i = blockIdx.x * blockDim.x + threadIdx.x;
    const float4* Xv = (const float4*)X;
    float4 a = Xv[i * 2 + 0];
    float4 b = Xv[i * 2 + 1];
    uint16_t o[8];
    o[0] = __bfloat16_as_ushort(__float2bfloat16(a.x));
    o[1] = __bfloat16_as_ushort(__float2bfloat16(a.y));
    o[2] = __bfloat16_as_ushort(__float2bfloat16(a.z));
    o[3] = __bfloat16_as_ushort(__float2bfloat16(a.w));
    o[4] = __bfloat16_as_ushort(__float2bfloat16(b.x));
    o[5] = __bfloat16_as_ushort(__float2bfloat16(b.y));
    o[6] = __bfloat16_as_ushort(__float2bfloat16(b.z));
    o[7] = __bfloat16_as_ushort(__float2bfloat16(b.w));
    *reinterpret_cast<uint4*>(Xb + (size_t)i * 8) = *reinterpret_cast<uint4*>(o);
  } else {
    // ---- Weff^T = (W + A@Bk)^T, [N][K] bf16 ----
    const int pid = blockIdx.x - CVT_BLOCKS;       // 0..1023
    const int tx = threadIdx.x & 63;
    const int ty = threadIdx.x >> 6;
    const int n0 = (pid & 31) * 64, k0 = (pid >> 5) * 64;

    const int n = n0 + tx;
    const float b0 = Bk[0 * Ndim + n];
    const float b1 = Bk[1 * Ndim + n];
    const float b2 = Bk[2 * Ndim + n];
    const float b3 = Bk[3 * Ndim + n];

    for (int i = ty; i < 64; i += 4) {
      const int k = k0 + i;
      float w = W[(size_t)k * Ndim + n];
      w += SCALE * (A[k * 4 + 0] * b0 + A[k * 4 + 1] * b1 +
                    A[k * 4 + 2] * b2 + A[k * 4 + 3] * b3);
      tile[tx][i] = w;                       // transposed into LDS
    }
    __syncthreads();
    for (int i = ty; i < 64; i += 4) {
      Wt[(size_t)(n0 + i) * Kdim + (k0 + tx)] =
          __bfloat16_as_ushort(__float2bfloat16(tile[i][tx]));
    }
  }
}

// ---------------- main GEMM: C = Xb @ Weff (Wt is Weff^T, K-major) --------
// LDS layout: As/Bs [128 rows][8 chunks of 16B]; physical chunk p at row r
// holds global chunk p ^ (r&7)  (swizzle applied via staging SOURCE address).
__global__ void gemm_bt(const uint16_t* __restrict__ X,
                        const uint16_t* __restrict__ Wt,
                        float* __restrict__ out) {
  __shared__ uint16_t As[BM * BK];  // 16 KB
  __shared__ uint16_t Bs[BN * BK];  // 16 KB

  const int t = threadIdx.x;
  const int wave = t >> 6, lane = t & 63;

  // XCD patch swizzle: xcd = lid&7 owns a 16(bx) x 8(by) patch.
  // Per-XCD L2 working set: 8 by-tiles of Xb (4 MB) + all Wt (8 MB).
  const int lid = blockIdx.x;          // 0..1023 (1D grid)
  const int s   = lid >> 3;            // 0..127 within XCD
  const int bx  = s & 15;              // 0..15
  const int by  = (lid & 7) * 8 + (s >> 4);  // 0..63
  const int m0 = by * BM, n0 = bx * BN;

  const int wm = wave & 1, wn = wave >> 1;  // 2x2 wave grid, 64x64 each
  const int l15 = lane & 15, kg = lane >> 4;
  const int sw = l15 & 7;                   // frag-read row swizzle key

  // staging: chunk = 8 rows x 64 cols (1 KB). 16 chunks per matrix.
  // lane -> row within chunk = lane>>3, physical 16B col = lane&7,
  // global 16B col = (lane&7) ^ (lane>>3)   [the XOR swizzle]
  const int r8 = lane >> 3;                 // 0..7
  const int gc = (lane & 7) ^ r8;           // swizzled global chunk col
  const uint16_t* Ag = X + (size_t)m0 * Kdim;
  const uint16_t* Bg = Wt + (size_t)n0 * Kdim;

  f32x4 acc[4][4] = {};

  for (int kt = 0; kt < Kdim; kt += BK) {
#pragma unroll
    for (int c = 0; c < 4; ++c) {
      const int ch = wave * 4 + c;          // 0..15
      const int row = ch * 8 + r8;          // tile-local row
      gload_lds16(Ag + (size_t)row * Kdim + kt + gc * 8, &As[ch * 512]);
      gload_lds16(Bg + (size_t)row * Kdim + kt + gc * 8, &Bs[ch * 512]);
    }
    __syncthreads();  // drains vmcnt -> tiles visible

#pragma unroll
    for (int s2 = 0; s2 < 2; ++s2) {        // two 16x16x32 k-steps per BK=64
      bf16x8 af[4], bfr[4];
      const int p = (s2 * 4 + kg) ^ sw;     // physical chunk for logical k-chunk
#pragma unroll
      for (int i = 0; i < 4; ++i) {
        const int ra = wm * 64 + i * 16 + l15;
        const int rb = wn * 64 + i * 16 + l15;
        af[i]  = *reinterpret_cast<const bf16x8*>(&As[ra * BK + p * 8]);
        bfr[i] = *reinterpret_cast<const bf16x8*>(&Bs[rb * BK + p * 8]);
      }
#pragma unroll
      for (int i = 0; i < 4; ++i)
#pragma unroll
        for (int j = 0; j < 4; ++j)
          acc[i][j] = __builtin_amdgcn_mfma_f32_16x16x32_bf16(af[i], bfr[j], acc[i][j], 0, 0, 0);
    }
    __syncthreads();  // before next stage overwrites tiles
  }

  // epilogue: C/D layout col = lane&15, row = (lane>>4)*4 + reg  [m89/m91]
#pragma unroll
  for (int i = 0; i < 4; ++i) {
    const int m_base = m0 + wm * 64 + i * 16 + kg * 4;
#pragma unroll
    for (int j = 0; j < 4; ++j) {
      const int n = n0 + wn * 64 + j * 16 + l15;
#pragma unroll
      for (int r = 0; r < 4; ++r) {
        out[(size_t)(m_base + r) * Ndim + n] = acc[i][j][r];
      }
    }
  }
}

extern "C" void kernel_launch(void* const* d_in, const int* in_sizes, int n_in,
                              void* d_out, int out_size, void* d_ws, size_t ws_size,
                              hipStream_t stream) {
  const float* x  = (const float*)d_in[0];  // [4,2048,2048]
  const float* W  = (const float*)d_in[1];  // [2048,16,128]
  const float* A  = (const float*)d_in[2];  // [2048,4]
  const float* Bk = (const float*)d_in[3];  // [4,16,128]
  float* out = (float*)d_out;               // [4,2048,16,128] fp32

  uint16_t* Xb = (uint16_t*)d_ws;                               // 32 MB
  uint16_t* Wt = (uint16_t*)((char*)d_ws + (size_t)Mdim * Kdim * 2);  // 8 MB

  // fused: X fp32->bf16  +  Weff^T build
  prep_all<<<CVT_BLOCKS + PREP_BLOCKS, 256, 0, stream>>>(x, W, A, Bk, Xb, Wt);

  // main GEMM (1D grid, XCD patch swizzle inside)
  gemm_bt<<<(Ndim / BN) * (Mdim / BM), 256, 0, stream>>>(Xb, Wt, out);
}